// Round 2
// baseline (2108.401 us; speedup 1.0000x reference)
//
#include <hip/hip_runtime.h>
#include <math.h>

// Needs ws_size >= 249,803,264 bytes (same as round 1).

#define NPT   25000
#define NN    100000
#define EE    600000
#define HD    128
#define NRELS 8

typedef unsigned short u16;
typedef unsigned int   u32;
using s16x8 = __attribute__((ext_vector_type(8))) short;
using f32x4 = __attribute__((ext_vector_type(4))) float;

__device__ __forceinline__ u16 f2bf(float x){
  u32 u = __float_as_uint(x);
  u += 0x7fffu + ((u >> 16) & 1u);
  return (u16)(u >> 16);
}
__device__ __forceinline__ float bf2f(u16 v){ return __uint_as_float(((u32)v) << 16); }

// ---------- weight cast+transpose: in [K][N] f32 -> out [N][K] bf16, batched on blockIdx.y
__global__ __launch_bounds__(256) void cast_tr(const float* __restrict__ in,
                                               u16* __restrict__ out, int K, int N){
  long b = blockIdx.y;
  const float* ib = in + b * (long)K * N;
  u16* ob = out + b * (long)K * N;
  int idx = blockIdx.x * 256 + threadIdx.x;
  if (idx < K * N){
    int n = idx / K, k = idx - n * K;
    ob[idx] = f2bf(ib[(long)k * N + n]);
  }
}

// ---------- relation-bucket counting sort (meta: [0..8)=hist, [8..16)=cursor, [16..25)=offsets)
__global__ __launch_bounds__(256) void hist_k(const int* __restrict__ et, int* meta){
  __shared__ int lh[NRELS];
  if (threadIdx.x < NRELS) lh[threadIdx.x] = 0;
  __syncthreads();
  int e = blockIdx.x * 256 + threadIdx.x;
  if (e < EE) atomicAdd(&lh[et[e]], 1);
  __syncthreads();
  if (threadIdx.x < NRELS && lh[threadIdx.x] > 0) atomicAdd(&meta[threadIdx.x], lh[threadIdx.x]);
}

__global__ void scan_k(int* meta){
  if (threadIdx.x == 0 && blockIdx.x == 0){
    int off = 0;
    for (int r = 0; r < NRELS; r++){ meta[16 + r] = off; meta[8 + r] = off; off += meta[r]; }
    meta[24] = off;
  }
}

__global__ __launch_bounds__(256) void scatter_k(const int* __restrict__ ei,
                                                 const int* __restrict__ et, int* meta,
                                                 int* __restrict__ ss, int* __restrict__ sd){
  __shared__ int lcount[NRELS], lbase[NRELS];
  if (threadIdx.x < NRELS) lcount[threadIdx.x] = 0;
  __syncthreads();
  int e = blockIdx.x * 256 + threadIdx.x;
  int r = 0, myrank = 0;
  if (e < EE){ r = et[e]; myrank = atomicAdd(&lcount[r], 1); }
  __syncthreads();
  if (threadIdx.x < NRELS && lcount[threadIdx.x] > 0)
    lbase[threadIdx.x] = atomicAdd(&meta[8 + threadIdx.x], lcount[threadIdx.x]);
  __syncthreads();
  if (e < EE){
    int p = lbase[r] + myrank;
    ss[p] = ei[e];
    sd[p] = ei[EE + e];
  }
}

// ---------- dst CSR build: hist over sd -> 2-level exclusive scan -> rowp/cursor -> dp scatter
__global__ __launch_bounds__(256) void hist_dst(const int* __restrict__ sd, int* __restrict__ hist){
  int e = blockIdx.x * 256 + threadIdx.x;
  if (e < EE) atomicAdd(&hist[sd[e]], 1);
}

__global__ __launch_bounds__(256) void scan_part(const int* __restrict__ hist, int* __restrict__ bsum){
  __shared__ int sh[256];
  int i = blockIdx.x * 256 + threadIdx.x;
  sh[threadIdx.x] = (i < NN) ? hist[i] : 0;
  __syncthreads();
  for (int s = 128; s > 0; s >>= 1){
    if (threadIdx.x < s) sh[threadIdx.x] += sh[threadIdx.x + s];
    __syncthreads();
  }
  if (threadIdx.x == 0) bsum[blockIdx.x] = sh[0];
}

__global__ __launch_bounds__(512) void scan_bsum(int* bsum, int nb){
  __shared__ int sh[512];
  int t = threadIdx.x;
  int orig = (t < nb) ? bsum[t] : 0;
  sh[t] = orig;
  __syncthreads();
  for (int off = 1; off < 512; off <<= 1){
    int u = (t >= off) ? sh[t - off] : 0;
    __syncthreads();
    sh[t] += u;
    __syncthreads();
  }
  if (t < nb) bsum[t] = sh[t] - orig;  // exclusive
}

__global__ __launch_bounds__(256) void scan_fin(const int* __restrict__ hist,
                                                const int* __restrict__ bsum,
                                                int* __restrict__ rowp, int* __restrict__ cursor){
  __shared__ int sh[256];
  int i = blockIdx.x * 256 + threadIdx.x;
  int v = (i < NN) ? hist[i] : 0;
  sh[threadIdx.x] = v;
  __syncthreads();
  for (int off = 1; off < 256; off <<= 1){
    int u = (threadIdx.x >= off) ? sh[threadIdx.x - off] : 0;
    __syncthreads();
    sh[threadIdx.x] += u;
    __syncthreads();
  }
  int excl = sh[threadIdx.x] - v + bsum[blockIdx.x];
  if (i < NN){ rowp[i] = excl; cursor[i] = excl; }
  if (i == NN - 1) rowp[NN] = excl + v;
}

__global__ __launch_bounds__(256) void dp_scat(const int* __restrict__ sd,
                                               int* __restrict__ cursor, int* __restrict__ dp){
  int e = blockIdx.x * 256 + threadIdx.x;
  if (e < EE) dp[e] = atomicAdd(&cursor[sd[e]], 1);
}

// ---------- bf16 MFMA GEMM: C[M][N] = act(A[M][K] @ Bt[N][K]^T + bias)
// A_F32: A is f32, cast while staging. Otherwise A is bf16.
template<bool A_F32, bool RELU, bool OUTF32, bool OUTBF16>
__global__ __launch_bounds__(256)
void gemm_k(const void* __restrict__ Ap, const u16* __restrict__ Bt,
            const float* __restrict__ bias,
            float* __restrict__ Cf, u16* __restrict__ Cbf,
            int M, int N, int K, int sAr, int sB, int sBias, int sCr)
{
  __shared__ __align__(16) u16 As[128 * 40];
  __shared__ __align__(16) u16 Bs[128 * 40];
  int z = blockIdx.z;
  int tid = threadIdx.x, wv = tid >> 6, lane = tid & 63;
  int m0 = blockIdx.x * 128, n0 = blockIdx.y * 128;
  int wm = (wv >> 1) * 64, wn = (wv & 1) * 64;
  long aBase = (long)z * sAr * K;
  const u16*   Ab  = (const u16*)Ap;
  const float* Afp = (const float*)Ap;
  const u16* Bz = Bt + (long)z * sB;
  const float* biz = bias + (long)z * sBias;
  long cRow0 = (long)z * sCr;
  int r2 = tid >> 1, hf = tid & 1;

  f32x4 acc[4][4];
  #pragma unroll
  for (int i = 0; i < 4; i++)
    #pragma unroll
    for (int j = 0; j < 4; j++) acc[i][j] = (f32x4){0.f, 0.f, 0.f, 0.f};

  for (int kk = 0; kk < K; kk += 32){
    {
      int gm = m0 + r2;
      #pragma unroll
      for (int c = 0; c < 2; c++){
        int ko = kk + c * 16 + hf * 8;
        union { u16 us[8]; uint4 v; } pk;
        if (gm < M){
          if (!A_F32){
            pk.v = *(const uint4*)(Ab + aBase + (long)gm * K + ko);
          } else {
            const float* s = Afp + aBase + (long)gm * K + ko;
            float4 f0 = *(const float4*)s;
            float4 f1 = *(const float4*)(s + 4);
            pk.us[0] = f2bf(f0.x); pk.us[1] = f2bf(f0.y); pk.us[2] = f2bf(f0.z); pk.us[3] = f2bf(f0.w);
            pk.us[4] = f2bf(f1.x); pk.us[5] = f2bf(f1.y); pk.us[6] = f2bf(f1.z); pk.us[7] = f2bf(f1.w);
          }
        } else {
          pk.v = make_uint4(0u, 0u, 0u, 0u);
        }
        *(uint4*)&As[r2 * 40 + c * 16 + hf * 8] = pk.v;
      }
    }
    {
      int gn = n0 + r2;
      #pragma unroll
      for (int c = 0; c < 2; c++){
        int ko = kk + c * 16 + hf * 8;
        uint4 v;
        if (gn < N) v = *(const uint4*)(Bz + (long)gn * K + ko);
        else        v = make_uint4(0u, 0u, 0u, 0u);
        *(uint4*)&Bs[r2 * 40 + c * 16 + hf * 8] = v;
      }
    }
    __syncthreads();
    s16x8 af[4], bfr[4];
    int rr = lane & 15, q8 = (lane >> 4) * 8;
    #pragma unroll
    for (int mt = 0; mt < 4; mt++) af[mt]  = *(const s16x8*)&As[(wm + mt * 16 + rr) * 40 + q8];
    #pragma unroll
    for (int nt = 0; nt < 4; nt++) bfr[nt] = *(const s16x8*)&Bs[(wn + nt * 16 + rr) * 40 + q8];
    #pragma unroll
    for (int mt = 0; mt < 4; mt++)
      #pragma unroll
      for (int nt = 0; nt < 4; nt++)
        acc[mt][nt] = __builtin_amdgcn_mfma_f32_16x16x32_bf16(af[mt], bfr[nt], acc[mt][nt], 0, 0, 0);
    __syncthreads();
  }
  int col = lane & 15, row4 = (lane >> 4) * 4;
  #pragma unroll
  for (int mt = 0; mt < 4; mt++){
    #pragma unroll
    for (int nt = 0; nt < 4; nt++){
      int gn = n0 + wn + nt * 16 + col;
      float bb = (gn < N) ? biz[gn] : 0.f;
      #pragma unroll
      for (int r = 0; r < 4; r++){
        int gm = m0 + wm + mt * 16 + row4 + r;
        if (gm < M && gn < N){
          float vv = acc[mt][nt][r] + bb;
          if (RELU) vv = fmaxf(vv, 0.f);
          long ci = (cRow0 + gm) * (long)N + gn;
          if (OUTF32)  Cf[ci]  = vv;
          if (OUTBF16) Cbf[ci] = f2bf(vv);
        }
      }
    }
  }
}

// ---------- edge pass A: att[dp[e]][h] = (q_d . (ra[r,h] k_s)) * rp[r,h] / sqrt(32). No atomics.
__global__ __launch_bounds__(256)
void edge_attn(const u16* __restrict__ kb, const u16* __restrict__ qb,
               const int* __restrict__ ss, const int* __restrict__ sd,
               const int* __restrict__ dp, const int* __restrict__ offs,
               const float* __restrict__ rel, const float* __restrict__ rp,
               float* __restrict__ att)
{
  int r = blockIdx.y;
  int lo = offs[r], hi = offs[r + 1];
  int base = lo + blockIdx.x * 128;
  if (base >= hi) return;
  int tid = threadIdx.x, wv = tid >> 6, lane = tid & 63;
  int f = lane & 31, hp = lane >> 5;
  int e0 = base + wv * 32;
  if (e0 >= hi) return;
  int e1 = min(hi, e0 + 32);
  const float* ra = rel + (long)r * 4096;
  float rA[32], rB[32];
  #pragma unroll
  for (int d = 0; d < 32; d++){
    rA[d] = ra[hp * 1024 + d * 32 + f];
    rB[d] = ra[(hp + 2) * 1024 + d * 32 + f];
  }
  float rpa = rp[r * 4 + hp]     * 0.17677669529663689f;
  float rpb = rp[r * 4 + hp + 2] * 0.17677669529663689f;
  for (int e = e0; e < e1; e++){
    int s_ = ss[e], dn = sd[e], po = dp[e];
    const uint4* kra = (const uint4*)(kb + (long)s_ * HD + hp * 32);
    const uint4* krb = (const uint4*)(kb + (long)s_ * HD + (hp + 2) * 32);
    float qa  = bf2f(qb[(long)dn * HD + lane]);
    float qb2 = bf2f(qb[(long)dn * HD + 64 + lane]);
    float sa0 = 0, sa1 = 0, sa2 = 0, sa3 = 0;
    float sb0 = 0, sb1 = 0, sb2 = 0, sb3 = 0;
    #pragma unroll
    for (int j = 0; j < 4; j++){
      uint4 ka = kra[j], kc = krb[j];
      u32 wa[4] = {ka.x, ka.y, ka.z, ka.w};
      u32 wb[4] = {kc.x, kc.y, kc.z, kc.w};
      #pragma unroll
      for (int t = 0; t < 4; t++){
        float a0 = __uint_as_float(wa[t] << 16);
        float a1 = __uint_as_float(wa[t] & 0xffff0000u);
        float b0 = __uint_as_float(wb[t] << 16);
        float b1 = __uint_as_float(wb[t] & 0xffff0000u);
        int d = j * 8 + t * 2;
        if (t & 1){ sa2 += a0 * rA[d]; sa3 += a1 * rA[d + 1]; sb2 += b0 * rB[d]; sb3 += b1 * rB[d + 1]; }
        else      { sa0 += a0 * rA[d]; sa1 += a1 * rA[d + 1]; sb0 += b0 * rB[d]; sb1 += b1 * rB[d + 1]; }
      }
    }
    float pa = qa  * ((sa0 + sa1) + (sa2 + sa3));
    float pb = qb2 * ((sb0 + sb1) + (sb2 + sb3));
    #pragma unroll
    for (int m = 1; m < 32; m <<= 1){ pa += __shfl_xor(pa, m); pb += __shfl_xor(pb, m); }
    if (f == 0){
      att[(long)po * 4 + hp]     = pa * rpa;
      att[(long)po * 4 + hp + 2] = pb * rpb;
    }
  }
}

// ---------- edge pass B: wt[dp[e]] = rm[r] v_s  (bf16 row, unweighted). No atomics.
__global__ __launch_bounds__(256)
void edge_mt(const u16* __restrict__ vb,
             const int* __restrict__ ss, const int* __restrict__ dp,
             const int* __restrict__ offs, const float* __restrict__ rel,
             u16* __restrict__ wt)
{
  int r = blockIdx.y;
  int lo = offs[r], hi = offs[r + 1];
  int base = lo + blockIdx.x * 128;
  if (base >= hi) return;
  int tid = threadIdx.x, wv = tid >> 6, lane = tid & 63;
  int f = lane & 31, hp = lane >> 5;
  int e0 = base + wv * 32;
  if (e0 >= hi) return;
  int e1 = min(hi, e0 + 32);
  const float* rm = rel + (long)r * 4096;
  float rA[32], rB[32];
  #pragma unroll
  for (int d = 0; d < 32; d++){
    rA[d] = rm[hp * 1024 + d * 32 + f];
    rB[d] = rm[(hp + 2) * 1024 + d * 32 + f];
  }
  for (int e = e0; e < e1; e++){
    int s_ = ss[e], po = dp[e];
    const uint4* vra = (const uint4*)(vb + (long)s_ * HD + hp * 32);
    const uint4* vrb = (const uint4*)(vb + (long)s_ * HD + (hp + 2) * 32);
    float sa0 = 0, sa1 = 0, sa2 = 0, sa3 = 0;
    float sb0 = 0, sb1 = 0, sb2 = 0, sb3 = 0;
    #pragma unroll
    for (int j = 0; j < 4; j++){
      uint4 va = vra[j], vc = vrb[j];
      u32 wa[4] = {va.x, va.y, va.z, va.w};
      u32 wb[4] = {vc.x, vc.y, vc.z, vc.w};
      #pragma unroll
      for (int t = 0; t < 4; t++){
        float a0 = __uint_as_float(wa[t] << 16);
        float a1 = __uint_as_float(wa[t] & 0xffff0000u);
        float b0 = __uint_as_float(wb[t] << 16);
        float b1 = __uint_as_float(wb[t] & 0xffff0000u);
        int d = j * 8 + t * 2;
        if (t & 1){ sa2 += a0 * rA[d]; sa3 += a1 * rA[d + 1]; sb2 += b0 * rB[d]; sb3 += b1 * rB[d + 1]; }
        else      { sa0 += a0 * rA[d]; sa1 += a1 * rA[d + 1]; sb0 += b0 * rB[d]; sb1 += b1 * rB[d + 1]; }
      }
    }
    float ma = (sa0 + sa1) + (sa2 + sa3);
    float mb = (sb0 + sb1) + (sb2 + sb3);
    wt[(long)po * HD + lane]      = f2bf(ma);
    wt[(long)po * HD + 64 + lane] = f2bf(mb);
  }
}

// ---------- per-dst segmented softmax + weighted sum + gelu -> bf16 A-row for Wa GEMM
__global__ __launch_bounds__(256)
void seg_reduce(const float* __restrict__ att, const u16* __restrict__ wt,
                const int* __restrict__ rowp, u16* __restrict__ gA)
{
  __shared__ __align__(16) float eas[4][64][4];
  int wv = threadIdx.x >> 6, lane = threadIdx.x & 63;
  int d = blockIdx.x * 4 + wv;
  if (d >= NN) return;
  int first = rowp[d], last = rowp[d + 1];
  int hsel = lane >> 5;                  // acc0 head = hsel, acc1 head = 2+hsel
  float m0 = -1e30f, m1 = -1e30f, m2 = -1e30f, m3 = -1e30f;
  float den0 = 0, den1 = 0, den2 = 0, den3 = 0;
  float acc0 = 0, acc1 = 0;
  for (int c0 = first; c0 < last; c0 += 64){
    int cnt = min(64, last - c0);
    float4 a;
    if (lane < cnt) a = *(const float4*)(att + (long)(c0 + lane) * 4);
    else            a = make_float4(-1e30f, -1e30f, -1e30f, -1e30f);
    float c_0 = a.x, c_1 = a.y, c_2 = a.z, c_3 = a.w;
    #pragma unroll
    for (int m = 1; m < 64; m <<= 1){
      c_0 = fmaxf(c_0, __shfl_xor(c_0, m));
      c_1 = fmaxf(c_1, __shfl_xor(c_1, m));
      c_2 = fmaxf(c_2, __shfl_xor(c_2, m));
      c_3 = fmaxf(c_3, __shfl_xor(c_3, m));
    }
    float n0 = fmaxf(m0, c_0), n1 = fmaxf(m1, c_1), n2 = fmaxf(m2, c_2), n3 = fmaxf(m3, c_3);
    float r0 = __expf(m0 - n0), r1 = __expf(m1 - n1), r2 = __expf(m2 - n2), r3 = __expf(m3 - n3);
    den0 *= r0; den1 *= r1; den2 *= r2; den3 *= r3;
    acc0 *= hsel ? r1 : r0;
    acc1 *= hsel ? r3 : r2;
    m0 = n0; m1 = n1; m2 = n2; m3 = n3;
    float e_0 = 0, e_1 = 0, e_2 = 0, e_3 = 0;
    if (lane < cnt){
      e_0 = __expf(a.x - m0); e_1 = __expf(a.y - m1);
      e_2 = __expf(a.z - m2); e_3 = __expf(a.w - m3);
    }
    float s0 = e_0, s1 = e_1, s2 = e_2, s3 = e_3;
    #pragma unroll
    for (int m = 1; m < 64; m <<= 1){
      s0 += __shfl_xor(s0, m); s1 += __shfl_xor(s1, m);
      s2 += __shfl_xor(s2, m); s3 += __shfl_xor(s3, m);
    }
    den0 += s0; den1 += s1; den2 += s2; den3 += s3;
    *(float4*)&eas[wv][lane][0] = make_float4(e_0, e_1, e_2, e_3);
    for (int i = 0; i < cnt; i++){
      float ea_a = eas[wv][i][hsel];
      float ea_b = eas[wv][i][2 + hsel];
      float w0 = bf2f(wt[(long)(c0 + i) * HD + lane]);
      float w1 = bf2f(wt[(long)(c0 + i) * HD + 64 + lane]);
      acc0 += ea_a * w0;
      acc1 += ea_b * w1;
    }
  }
  float dh0 = hsel ? den1 : den0;
  float dh1 = hsel ? den3 : den2;
  float x0 = acc0 / fmaxf(dh0, 1e-9f);
  float x1 = acc1 / fmaxf(dh1, 1e-9f);
  x0 = 0.5f * x0 * (1.0f + erff(x0 * 0.70710678118654752f));
  x1 = 0.5f * x1 * (1.0f + erff(x1 * 0.70710678118654752f));
  gA[(long)d * HD + lane]      = f2bf(x0);
  gA[(long)d * HD + 64 + lane] = f2bf(x1);
}

// ---------- skip-combine + LayerNorm; writes h (f32, = d_out) and bf16 mirror
__global__ __launch_bounds__(256)
void combine_ln(const float* __restrict__ trans, float* __restrict__ h,
                u16* __restrict__ hb, const float* __restrict__ skl,
                const float* __restrict__ gm, const float* __restrict__ bt)
{
  int wv = threadIdx.x >> 6, lane = threadIdx.x & 63;
  int node = blockIdx.x * 4 + wv;
  if (node >= NN) return;
  int t = node / NPT;
  float alpha = 1.f / (1.f + __expf(-skl[t]));
  long b0 = (long)node * HD;
  float x0 = trans[b0 + lane]      * alpha + h[b0 + lane]      * (1.f - alpha);
  float x1 = trans[b0 + 64 + lane] * alpha + h[b0 + 64 + lane] * (1.f - alpha);
  float s = x0 + x1;
  #pragma unroll
  for (int m = 1; m < 64; m <<= 1) s += __shfl_xor(s, m);
  float mean = s * (1.f / HD);
  float d0 = x0 - mean, d1 = x1 - mean;
  float vs = d0 * d0 + d1 * d1;
  #pragma unroll
  for (int m = 1; m < 64; m <<= 1) vs += __shfl_xor(vs, m);
  float rstd = rsqrtf(vs * (1.f / HD) + 1e-5f);
  float y0 = d0 * rstd * gm[lane]      + bt[lane];
  float y1 = d1 * rstd * gm[64 + lane] + bt[64 + lane];
  h[b0 + lane] = y0;        h[b0 + 64 + lane] = y1;
  hb[b0 + lane] = f2bf(y0); hb[b0 + 64 + lane] = f2bf(y1);
}

extern "C" void kernel_launch(void* const* d_in, const int* in_sizes, int n_in,
                              void* d_out, int out_size, void* d_ws, size_t ws_size,
                              hipStream_t stream)
{
  const float* nf[4]  = {(const float*)d_in[0], (const float*)d_in[1], (const float*)d_in[2], (const float*)d_in[3]};
  const float* ew1[4] = {(const float*)d_in[4], (const float*)d_in[8],  (const float*)d_in[12], (const float*)d_in[16]};
  const float* eb1[4] = {(const float*)d_in[5], (const float*)d_in[9],  (const float*)d_in[13], (const float*)d_in[17]};
  const float* ew2[4] = {(const float*)d_in[6], (const float*)d_in[10], (const float*)d_in[14], (const float*)d_in[18]};
  const float* eb2[4] = {(const float*)d_in[7], (const float*)d_in[11], (const float*)d_in[15], (const float*)d_in[19]};
  const float* Wk = (const float*)d_in[20]; const float* bk = (const float*)d_in[21];
  const float* Wq = (const float*)d_in[22]; const float* bq = (const float*)d_in[23];
  const float* Wv = (const float*)d_in[24]; const float* bv = (const float*)d_in[25];
  const float* Wa = (const float*)d_in[26]; const float* ba = (const float*)d_in[27];
  const float* rel_att = (const float*)d_in[28];
  const float* rel_msg = (const float*)d_in[29];
  const float* rel_pri = (const float*)d_in[30];
  const float* skp = (const float*)d_in[31];
  const float* gma = (const float*)d_in[32];
  const float* bta = (const float*)d_in[33];
  const int* edge_index = (const int*)d_in[35];
  const int* edge_types = (const int*)d_in[36];
  float* out = (float*)d_out;
  char* ws = (char*)d_ws;

  // ---- workspace map (lifetime-aliased; peak < 249.81 MB) ----
  u16*   vb    = (u16*)  (ws + 0L);            // 25.6 MB  kqv bf16
  u16*   kb    = (u16*)  (ws + 25600000L);     // 25.6 MB
  u16*   qb    = (u16*)  (ws + 51200000L);     // 25.6 MB
  u16*   gA    = (u16*)  (ws + 51200000L);     // aliases qb (dead at seg_reduce)
  float* trans = (float*)(ws + 0L);            // 51.2 MB, aliases vb+kb (dead at Wa/combine)
  u16*   wt    = (u16*)  (ws + 76800000L);     // 153.6 MB -> ends 230.4 MB
  u16*   hbf   = (u16*)  (ws + 76800000L);     // 25.6 MB, aliases wt head (disjoint lifetime)
  u16*   hid   = (u16*)  (ws + 102400000L);    // 12.8 MB encoder tmp, aliases wt
  float* attb  = (float*)(ws + 230400000L);    // 9.6 MB -> 240.0 MB
  int*   bsum  = (int*)  (ws + 230400000L);    // scan tmp, aliases attb (pre-layer only)
  int*   ss    = (int*)  (ws + 240000000L);    // 2.4 MB
  int*   sd    = (int*)  (ws + 242400000L);    // 2.4 MB
  int*   dp    = (int*)  (ws + 244800000L);    // 2.4 MB
  int*   rowp  = (int*)  (ws + 247200000L);    // 400,128 B
  int*   curs  = (int*)  (ws + 247600128L);    // 400,000 B (also dst-hist)
  int*   meta  = (int*)  (ws + 248000128L);    // 256 B
  u16*   w1t   = (u16*)  (ws + 248000384L);
  u16*   w2t   = (u16*)  (ws + 248491904L);
  u16*   wkt   = (u16*)  (ws + 248754048L);
  u16*   wqt   = (u16*)  (ws + 249016192L);
  u16*   wvt   = (u16*)  (ws + 249278336L);
  u16*   wat   = (u16*)  (ws + 249540480L);

  int  di[4]  = {512, 256, 128, 64};
  long w1o[4] = {0, 131072, 196608, 229376};

  // weight casts (f32 [K][N] -> bf16 [N][K])
  for (int i = 0; i < 4; i++){
    cast_tr<<<dim3(di[i], 1), 256, 0, stream>>>(ew1[i], w1t + w1o[i], di[i], 256);
    cast_tr<<<dim3(128, 1),  256, 0, stream>>>(ew2[i], w2t + (long)i * 32768, 256, 128);
  }
  cast_tr<<<dim3(64, 8), 256, 0, stream>>>(Wk, wkt, 128, 128);
  cast_tr<<<dim3(64, 8), 256, 0, stream>>>(Wq, wqt, 128, 128);
  cast_tr<<<dim3(64, 8), 256, 0, stream>>>(Wv, wvt, 128, 128);
  cast_tr<<<dim3(64, 8), 256, 0, stream>>>(Wa, wat, 128, 128);

  // relation bucket sort
  hipMemsetAsync(meta, 0, 256, stream);
  hist_k   <<<2344, 256, 0, stream>>>(edge_types, meta);
  scan_k   <<<1, 64, 0, stream>>>(meta);
  scatter_k<<<2344, 256, 0, stream>>>(edge_index, edge_types, meta, ss, sd);

  // dst CSR + dp permutation (curs doubles as dst histogram)
  hipMemsetAsync(curs, 0, 400000, stream);
  hist_dst <<<2344, 256, 0, stream>>>(sd, curs);
  scan_part<<<391, 256, 0, stream>>>(curs, bsum);
  scan_bsum<<<1, 512, 0, stream>>>(bsum, 391);
  scan_fin <<<391, 256, 0, stream>>>(curs, bsum, rowp, curs);
  dp_scat  <<<2344, 256, 0, stream>>>(sd, curs, dp);

  // encoders: h = relu(nf@w1+b1)@w2 + b2  -> out (f32) + hbf (bf16)
  for (int i = 0; i < 4; i++){
    gemm_k<true,  true,  false, true><<<dim3(196, 2, 1), 256, 0, stream>>>(
        nf[i], w1t + w1o[i], eb1[i], nullptr, hid, NPT, 256, di[i], 0, 0, 0, 0);
    gemm_k<false, false, true,  true><<<dim3(196, 1, 1), 256, 0, stream>>>(
        hid, w2t + (long)i * 32768, eb2[i],
        out + (long)i * NPT * HD, hbf + (long)i * NPT * HD, NPT, 128, 256, 0, 0, 0, 0);
  }

  for (int l = 0; l < 2; l++){
    // typed K,Q,V (batched over types on blockIdx.z), bf16 outputs
    gemm_k<false, false, false, true><<<dim3(196, 1, 4), 256, 0, stream>>>(
        hbf, wkt + (long)l * 65536, bk + l * 512, nullptr, kb,
        NPT, 128, 128, NPT, 16384, 128, NPT);
    gemm_k<false, false, false, true><<<dim3(196, 1, 4), 256, 0, stream>>>(
        hbf, wqt + (long)l * 65536, bq + l * 512, nullptr, qb,
        NPT, 128, 128, NPT, 16384, 128, NPT);
    gemm_k<false, false, false, true><<<dim3(196, 1, 4), 256, 0, stream>>>(
        hbf, wvt + (long)l * 65536, bv + l * 512, nullptr, vb,
        NPT, 128, 128, NPT, 16384, 128, NPT);

    edge_attn<<<dim3(700, 8), 256, 0, stream>>>(
        kb, qb, ss, sd, dp, meta + 16,
        rel_att + (long)l * 32768, rel_pri + l * 32, attb);
    edge_mt<<<dim3(700, 8), 256, 0, stream>>>(
        vb, ss, dp, meta + 16,
        rel_msg + (long)l * 32768, wt);

    seg_reduce<<<25000, 256, 0, stream>>>(attb, wt, rowp, gA);

    // trans = gelu_msg @ Wa + ba  (f32 into trans)
    gemm_k<false, false, true, false><<<dim3(196, 1, 4), 256, 0, stream>>>(
        gA, wat + (long)l * 65536, ba + l * 512, trans, nullptr,
        NPT, 128, 128, NPT, 16384, 128, NPT);

    combine_ln<<<25000, 256, 0, stream>>>(
        trans, out, hbf, skp + l * 4, gma + l * 128, bta + l * 128);
  }
}

// Round 3
// 1465.891 us; speedup vs baseline: 1.4383x; 1.4383x over previous
//
#include <hip/hip_runtime.h>
#include <math.h>

// Needs ws_size >= 249,803,264 bytes.

#define NPT   25000
#define NN    100000
#define EE    600000
#define HD    128
#define NRELS 8

typedef unsigned short u16;
typedef unsigned int   u32;
using s16x8 = __attribute__((ext_vector_type(8))) short;
using f32x4 = __attribute__((ext_vector_type(4))) float;

__device__ __forceinline__ u16 f2bf(float x){
  u32 u = __float_as_uint(x);
  u += 0x7fffu + ((u >> 16) & 1u);
  return (u16)(u >> 16);
}
__device__ __forceinline__ float bf2f(u16 v){ return __uint_as_float(((u32)v) << 16); }

// ---------- weight cast+transpose: in [K][N] f32 -> out [N][K] bf16, batched on blockIdx.y
__global__ __launch_bounds__(256) void cast_tr(const float* __restrict__ in,
                                               u16* __restrict__ out, int K, int N){
  long b = blockIdx.y;
  const float* ib = in + b * (long)K * N;
  u16* ob = out + b * (long)K * N;
  int idx = blockIdx.x * 256 + threadIdx.x;
  if (idx < K * N){
    int n = idx / K, k = idx - n * K;
    ob[idx] = f2bf(ib[(long)k * N + n]);
  }
}

// ---------- pack rel_att/rel_msg into MFMA B-frag bf16 layout
__global__ __launch_bounds__(256) void pack_rel(const float* __restrict__ ra,
                                                const float* __restrict__ rm,
                                                u16* __restrict__ out){
  int idx = blockIdx.x * 256 + threadIdx.x;
  if (idx >= 131072) return;
  int j = idx & 7, lane = (idx >> 3) & 63, nc = (idx >> 9) & 1;
  int h = (idx >> 10) & 3, r = (idx >> 12) & 7, mat = (idx >> 15) & 1, l = idx >> 16;
  const float* src = mat ? rm : ra;
  float v = src[(((long)l * 8 + r) * 4 + h) * 1024 + ((lane >> 4) * 8 + j) * 32 + nc * 16 + (lane & 15)];
  out[idx] = f2bf(v);
}

// ---------- relation-bucket counting sort (meta: [0..8)=hist, [8..16)=cursor, [16..25)=offsets)
__global__ __launch_bounds__(256) void hist_k(const int* __restrict__ et, int* meta){
  __shared__ int lh[NRELS];
  if (threadIdx.x < NRELS) lh[threadIdx.x] = 0;
  __syncthreads();
  int e = blockIdx.x * 256 + threadIdx.x;
  if (e < EE) atomicAdd(&lh[et[e]], 1);
  __syncthreads();
  if (threadIdx.x < NRELS && lh[threadIdx.x] > 0) atomicAdd(&meta[threadIdx.x], lh[threadIdx.x]);
}

__global__ void scan_k(int* meta){
  if (threadIdx.x == 0 && blockIdx.x == 0){
    int off = 0;
    for (int r = 0; r < NRELS; r++){ meta[16 + r] = off; meta[8 + r] = off; off += meta[r]; }
    meta[24] = off;
  }
}

__global__ __launch_bounds__(256) void scatter_k(const int* __restrict__ ei,
                                                 const int* __restrict__ et, int* meta,
                                                 int* __restrict__ ss, int* __restrict__ sd){
  __shared__ int lcount[NRELS], lbase[NRELS];
  if (threadIdx.x < NRELS) lcount[threadIdx.x] = 0;
  __syncthreads();
  int e = blockIdx.x * 256 + threadIdx.x;
  int r = 0, myrank = 0;
  if (e < EE){ r = et[e]; myrank = atomicAdd(&lcount[r], 1); }
  __syncthreads();
  if (threadIdx.x < NRELS && lcount[threadIdx.x] > 0)
    lbase[threadIdx.x] = atomicAdd(&meta[8 + threadIdx.x], lcount[threadIdx.x]);
  __syncthreads();
  if (e < EE){
    int p = lbase[r] + myrank;
    ss[p] = ei[e];
    sd[p] = ei[EE + e];
  }
}

// ---------- dst CSR build
__global__ __launch_bounds__(256) void hist_dst(const int* __restrict__ sd, int* __restrict__ hist){
  int e = blockIdx.x * 256 + threadIdx.x;
  if (e < EE) atomicAdd(&hist[sd[e]], 1);
}

__global__ __launch_bounds__(256) void scan_part(const int* __restrict__ hist, int* __restrict__ bsum){
  __shared__ int sh[256];
  int i = blockIdx.x * 256 + threadIdx.x;
  sh[threadIdx.x] = (i < NN) ? hist[i] : 0;
  __syncthreads();
  for (int s = 128; s > 0; s >>= 1){
    if (threadIdx.x < s) sh[threadIdx.x] += sh[threadIdx.x + s];
    __syncthreads();
  }
  if (threadIdx.x == 0) bsum[blockIdx.x] = sh[0];
}

__global__ __launch_bounds__(512) void scan_bsum(int* bsum, int nb){
  __shared__ int sh[512];
  int t = threadIdx.x;
  int orig = (t < nb) ? bsum[t] : 0;
  sh[t] = orig;
  __syncthreads();
  for (int off = 1; off < 512; off <<= 1){
    int u = (t >= off) ? sh[t - off] : 0;
    __syncthreads();
    sh[t] += u;
    __syncthreads();
  }
  if (t < nb) bsum[t] = sh[t] - orig;  // exclusive
}

__global__ __launch_bounds__(256) void scan_fin(const int* __restrict__ hist,
                                                const int* __restrict__ bsum,
                                                int* __restrict__ rowp, int* __restrict__ cursor){
  __shared__ int sh[256];
  int i = blockIdx.x * 256 + threadIdx.x;
  int v = (i < NN) ? hist[i] : 0;
  sh[threadIdx.x] = v;
  __syncthreads();
  for (int off = 1; off < 256; off <<= 1){
    int u = (threadIdx.x >= off) ? sh[threadIdx.x - off] : 0;
    __syncthreads();
    sh[threadIdx.x] += u;
    __syncthreads();
  }
  int excl = sh[threadIdx.x] - v + bsum[blockIdx.x];
  if (i < NN){ rowp[i] = excl; cursor[i] = excl; }
  if (i == NN - 1) rowp[NN] = excl + v;
}

__global__ __launch_bounds__(256) void dp_scat(const int* __restrict__ sd,
                                               int* __restrict__ cursor, int* __restrict__ dp){
  int e = blockIdx.x * 256 + threadIdx.x;
  if (e < EE) dp[e] = atomicAdd(&cursor[sd[e]], 1);
}

// ---------- bf16 MFMA GEMM: C[M][N] = act(A[M][K] @ Bt[N][K]^T + bias)
template<bool A_F32, bool RELU, bool OUTF32, bool OUTBF16>
__global__ __launch_bounds__(256)
void gemm_k(const void* __restrict__ Ap, const u16* __restrict__ Bt,
            const float* __restrict__ bias,
            float* __restrict__ Cf, u16* __restrict__ Cbf,
            int M, int N, int K, int sAr, int sB, int sBias, int sCr,
            int ldC, int colOff)
{
  __shared__ __align__(16) u16 As[128 * 40];
  __shared__ __align__(16) u16 Bs[128 * 40];
  int z = blockIdx.z;
  int tid = threadIdx.x, wv = tid >> 6, lane = tid & 63;
  int m0 = blockIdx.x * 128, n0 = blockIdx.y * 128;
  int wm = (wv >> 1) * 64, wn = (wv & 1) * 64;
  long aBase = (long)z * sAr * K;
  const u16*   Ab  = (const u16*)Ap;
  const float* Afp = (const float*)Ap;
  const u16* Bz = Bt + (long)z * sB;
  const float* biz = bias + (long)z * sBias;
  long cRow0 = (long)z * sCr;
  int r2 = tid >> 1, hf = tid & 1;

  f32x4 acc[4][4];
  #pragma unroll
  for (int i = 0; i < 4; i++)
    #pragma unroll
    for (int j = 0; j < 4; j++) acc[i][j] = (f32x4){0.f, 0.f, 0.f, 0.f};

  for (int kk = 0; kk < K; kk += 32){
    {
      int gm = m0 + r2;
      #pragma unroll
      for (int c = 0; c < 2; c++){
        int ko = kk + c * 16 + hf * 8;
        union { u16 us[8]; uint4 v; } pk;
        if (gm < M){
          if (!A_F32){
            pk.v = *(const uint4*)(Ab + aBase + (long)gm * K + ko);
          } else {
            const float* s = Afp + aBase + (long)gm * K + ko;
            float4 f0 = *(const float4*)s;
            float4 f1 = *(const float4*)(s + 4);
            pk.us[0] = f2bf(f0.x); pk.us[1] = f2bf(f0.y); pk.us[2] = f2bf(f0.z); pk.us[3] = f2bf(f0.w);
            pk.us[4] = f2bf(f1.x); pk.us[5] = f2bf(f1.y); pk.us[6] = f2bf(f1.z); pk.us[7] = f2bf(f1.w);
          }
        } else {
          pk.v = make_uint4(0u, 0u, 0u, 0u);
        }
        *(uint4*)&As[r2 * 40 + c * 16 + hf * 8] = pk.v;
      }
    }
    {
      int gn = n0 + r2;
      #pragma unroll
      for (int c = 0; c < 2; c++){
        int ko = kk + c * 16 + hf * 8;
        uint4 v;
        if (gn < N) v = *(const uint4*)(Bz + (long)gn * K + ko);
        else        v = make_uint4(0u, 0u, 0u, 0u);
        *(uint4*)&Bs[r2 * 40 + c * 16 + hf * 8] = v;
      }
    }
    __syncthreads();
    s16x8 af[4], bfr[4];
    int rr = lane & 15, q8 = (lane >> 4) * 8;
    #pragma unroll
    for (int mt = 0; mt < 4; mt++) af[mt]  = *(const s16x8*)&As[(wm + mt * 16 + rr) * 40 + q8];
    #pragma unroll
    for (int nt = 0; nt < 4; nt++) bfr[nt] = *(const s16x8*)&Bs[(wn + nt * 16 + rr) * 40 + q8];
    #pragma unroll
    for (int mt = 0; mt < 4; mt++)
      #pragma unroll
      for (int nt = 0; nt < 4; nt++)
        acc[mt][nt] = __builtin_amdgcn_mfma_f32_16x16x32_bf16(af[mt], bfr[nt], acc[mt][nt], 0, 0, 0);
    __syncthreads();
  }
  int col = lane & 15, row4 = (lane >> 4) * 4;
  #pragma unroll
  for (int mt = 0; mt < 4; mt++){
    #pragma unroll
    for (int nt = 0; nt < 4; nt++){
      int gn = n0 + wn + nt * 16 + col;
      float bb = (gn < N) ? biz[gn] : 0.f;
      #pragma unroll
      for (int r = 0; r < 4; r++){
        int gm = m0 + wm + mt * 16 + row4 + r;
        if (gm < M && gn < N){
          float vv = acc[mt][nt][r] + bb;
          if (RELU) vv = fmaxf(vv, 0.f);
          long ci = (cRow0 + gm) * (long)ldC + colOff + gn;
          if (OUTF32)  Cf[ci]  = vv;
          if (OUTBF16) Cbf[ci] = f2bf(vv);
        }
      }
    }
  }
}

// ---------- fused edge kernel: per (relation, 64-edge tile), 4 waves x 16 edges.
__global__ __launch_bounds__(256)
void edge_fused(const u16* __restrict__ kvb, const u16* __restrict__ qb,
                const int* __restrict__ ss, const int* __restrict__ sd,
                const int* __restrict__ dp, const int* __restrict__ offs,
                const u16* __restrict__ relpk, const float* __restrict__ rp,
                float* __restrict__ att, u16* __restrict__ wt, int l)
{
  __shared__ __align__(16) u16 ktS[4][16][136];
  int r = blockIdx.y;
  int lo = offs[r], hi = offs[r + 1];
  int base = lo + blockIdx.x * 64;
  if (base >= hi) return;
  int cnt = hi - base; if (cnt > 64) cnt = 64;
  int tid = threadIdx.x, wv = tid >> 6, lane = tid & 63;
  if (wv * 16 >= cnt) return;
  int wcnt = cnt - wv * 16; if (wcnt > 16) wcnt = 16;
  int m = lane & 15, g = lane >> 4;
  int ebase = base + wv * 16;
  int mm = (m < wcnt) ? m : (wcnt - 1);
  int s_ = ss[ebase + mm];
  const u16* krow = kvb + (long)s_ * 256;

  // ---- phase 1: kt = k @ RA via MFMA (A-frag gathered directly from global)
  s16x8 ak[4];
  #pragma unroll
  for (int h = 0; h < 4; h++) ak[h] = *(const s16x8*)(krow + h * 32 + g * 8);
  const u16* relA = relpk + (((long)l * 2) * 8 + r) * 4096;
  f32x4 tt[4][2];
  #pragma unroll
  for (int h = 0; h < 4; h++)
    #pragma unroll
    for (int nc = 0; nc < 2; nc++){
      s16x8 b = *(const s16x8*)(relA + h * 1024 + nc * 512 + lane * 8);
      tt[h][nc] = __builtin_amdgcn_mfma_f32_16x16x32_bf16(ak[h], b, (f32x4){0.f,0.f,0.f,0.f}, 0, 0, 0);
    }
  int col = lane & 15, row4 = (lane >> 4) * 4;
  #pragma unroll
  for (int h = 0; h < 4; h++)
    #pragma unroll
    for (int nc = 0; nc < 2; nc++)
      #pragma unroll
      for (int rr = 0; rr < 4; rr++)
        ktS[wv][row4 + rr][h * 32 + nc * 16 + col] = f2bf(tt[h][nc][rr]);
  __asm__ volatile("s_waitcnt lgkmcnt(0)" ::: "memory");

  // ---- att dot: lane covers dims [2*lane, 2*lane+1]; head = g
  float rsc = rp[r * 4 + g] * 0.17677669529663689f;
  for (int i = 0; i < wcnt; i++){
    int e = ebase + i;
    int dn = sd[e];
    u32 kk = *(const u32*)&ktS[wv][i][2 * lane];
    u32 qq = *(const u32*)(qb + (long)dn * 128 + 2 * lane);
    float p = bf2f((u16)(kk & 0xffffu)) * bf2f((u16)(qq & 0xffffu))
            + __uint_as_float(kk & 0xffff0000u) * __uint_as_float(qq & 0xffff0000u);
    p += __shfl_xor(p, 1); p += __shfl_xor(p, 2);
    p += __shfl_xor(p, 4); p += __shfl_xor(p, 8);
    if (m == 0) att[(long)dp[e] * 4 + g] = p * rsc;
  }
  __asm__ volatile("s_waitcnt lgkmcnt(0)" ::: "memory");

  // ---- phase 2: mt = v @ RM via MFMA
  s16x8 av[4];
  #pragma unroll
  for (int h = 0; h < 4; h++) av[h] = *(const s16x8*)(krow + 128 + h * 32 + g * 8);
  const u16* relM = relpk + (((long)l * 2 + 1) * 8 + r) * 4096;
  #pragma unroll
  for (int h = 0; h < 4; h++)
    #pragma unroll
    for (int nc = 0; nc < 2; nc++){
      s16x8 b = *(const s16x8*)(relM + h * 1024 + nc * 512 + lane * 8);
      tt[h][nc] = __builtin_amdgcn_mfma_f32_16x16x32_bf16(av[h], b, (f32x4){0.f,0.f,0.f,0.f}, 0, 0, 0);
    }
  #pragma unroll
  for (int h = 0; h < 4; h++)
    #pragma unroll
    for (int nc = 0; nc < 2; nc++)
      #pragma unroll
      for (int rr = 0; rr < 4; rr++)
        ktS[wv][row4 + rr][h * 32 + nc * 16 + col] = f2bf(tt[h][nc][rr]);
  __asm__ volatile("s_waitcnt lgkmcnt(0)" ::: "memory");

  // ---- coalesced writeout: 4 lanes per row, 64 B each
  int orow = lane >> 2, opart = lane & 3;
  if (orow < wcnt){
    int po = dp[ebase + orow];
    #pragma unroll
    for (int j = 0; j < 4; j++){
      uint4 v = *(const uint4*)&ktS[wv][orow][opart * 32 + j * 8];
      *(uint4*)(wt + (long)po * 128 + opart * 32 + j * 8) = v;
    }
  }
}

// ---------- per-dst segmented softmax + weighted sum + gelu -> bf16 A-row for Wa GEMM
__global__ __launch_bounds__(256)
void seg_reduce(const float* __restrict__ att, const u16* __restrict__ wt,
                const int* __restrict__ rowp, u16* __restrict__ gA)
{
  __shared__ __align__(16) float eas[4][64][4];
  int wv = threadIdx.x >> 6, lane = threadIdx.x & 63;
  int d = blockIdx.x * 4 + wv;
  if (d >= NN) return;
  int first = rowp[d], last = rowp[d + 1];
  int hsel = lane >> 5;
  float m0 = -1e30f, m1 = -1e30f, m2 = -1e30f, m3 = -1e30f;
  float den0 = 0, den1 = 0, den2 = 0, den3 = 0;
  float acc0 = 0, acc1 = 0;
  for (int c0 = first; c0 < last; c0 += 64){
    int cnt = min(64, last - c0);
    float4 a;
    if (lane < cnt) a = *(const float4*)(att + (long)(c0 + lane) * 4);
    else            a = make_float4(-1e30f, -1e30f, -1e30f, -1e30f);
    float c_0 = a.x, c_1 = a.y, c_2 = a.z, c_3 = a.w;
    #pragma unroll
    for (int m = 1; m < 64; m <<= 1){
      c_0 = fmaxf(c_0, __shfl_xor(c_0, m));
      c_1 = fmaxf(c_1, __shfl_xor(c_1, m));
      c_2 = fmaxf(c_2, __shfl_xor(c_2, m));
      c_3 = fmaxf(c_3, __shfl_xor(c_3, m));
    }
    float n0 = fmaxf(m0, c_0), n1 = fmaxf(m1, c_1), n2 = fmaxf(m2, c_2), n3 = fmaxf(m3, c_3);
    float r0 = __expf(m0 - n0), r1 = __expf(m1 - n1), r2 = __expf(m2 - n2), r3 = __expf(m3 - n3);
    den0 *= r0; den1 *= r1; den2 *= r2; den3 *= r3;
    acc0 *= hsel ? r1 : r0;
    acc1 *= hsel ? r3 : r2;
    m0 = n0; m1 = n1; m2 = n2; m3 = n3;
    float e_0 = 0, e_1 = 0, e_2 = 0, e_3 = 0;
    if (lane < cnt){
      e_0 = __expf(a.x - m0); e_1 = __expf(a.y - m1);
      e_2 = __expf(a.z - m2); e_3 = __expf(a.w - m3);
    }
    float s0 = e_0, s1 = e_1, s2 = e_2, s3 = e_3;
    #pragma unroll
    for (int m = 1; m < 64; m <<= 1){
      s0 += __shfl_xor(s0, m); s1 += __shfl_xor(s1, m);
      s2 += __shfl_xor(s2, m); s3 += __shfl_xor(s3, m);
    }
    den0 += s0; den1 += s1; den2 += s2; den3 += s3;
    *(float4*)&eas[wv][lane][0] = make_float4(e_0, e_1, e_2, e_3);
    for (int i = 0; i < cnt; i++){
      float ea_a = eas[wv][i][hsel];
      float ea_b = eas[wv][i][2 + hsel];
      float w0 = bf2f(wt[(long)(c0 + i) * HD + lane]);
      float w1 = bf2f(wt[(long)(c0 + i) * HD + 64 + lane]);
      acc0 += ea_a * w0;
      acc1 += ea_b * w1;
    }
  }
  float dh0 = hsel ? den1 : den0;
  float dh1 = hsel ? den3 : den2;
  float x0 = acc0 / fmaxf(dh0, 1e-9f);
  float x1 = acc1 / fmaxf(dh1, 1e-9f);
  x0 = 0.5f * x0 * (1.0f + erff(x0 * 0.70710678118654752f));
  x1 = 0.5f * x1 * (1.0f + erff(x1 * 0.70710678118654752f));
  gA[(long)d * HD + lane]      = f2bf(x0);
  gA[(long)d * HD + 64 + lane] = f2bf(x1);
}

// ---------- skip-combine + LayerNorm; writes h (f32, = d_out) and bf16 mirror
__global__ __launch_bounds__(256)
void combine_ln(const float* __restrict__ trans, float* __restrict__ h,
                u16* __restrict__ hb, const float* __restrict__ skl,
                const float* __restrict__ gm, const float* __restrict__ bt)
{
  int wv = threadIdx.x >> 6, lane = threadIdx.x & 63;
  int node = blockIdx.x * 4 + wv;
  if (node >= NN) return;
  int t = node / NPT;
  float alpha = 1.f / (1.f + __expf(-skl[t]));
  long b0 = (long)node * HD;
  float x0 = trans[b0 + lane]      * alpha + h[b0 + lane]      * (1.f - alpha);
  float x1 = trans[b0 + 64 + lane] * alpha + h[b0 + 64 + lane] * (1.f - alpha);
  float s = x0 + x1;
  #pragma unroll
  for (int m = 1; m < 64; m <<= 1) s += __shfl_xor(s, m);
  float mean = s * (1.f / HD);
  float d0 = x0 - mean, d1 = x1 - mean;
  float vs = d0 * d0 + d1 * d1;
  #pragma unroll
  for (int m = 1; m < 64; m <<= 1) vs += __shfl_xor(vs, m);
  float rstd = rsqrtf(vs * (1.f / HD) + 1e-5f);
  float y0 = d0 * rstd * gm[lane]      + bt[lane];
  float y1 = d1 * rstd * gm[64 + lane] + bt[64 + lane];
  h[b0 + lane] = y0;        h[b0 + 64 + lane] = y1;
  hb[b0 + lane] = f2bf(y0); hb[b0 + 64 + lane] = f2bf(y1);
}

extern "C" void kernel_launch(void* const* d_in, const int* in_sizes, int n_in,
                              void* d_out, int out_size, void* d_ws, size_t ws_size,
                              hipStream_t stream)
{
  const float* nf[4]  = {(const float*)d_in[0], (const float*)d_in[1], (const float*)d_in[2], (const float*)d_in[3]};
  const float* ew1[4] = {(const float*)d_in[4], (const float*)d_in[8],  (const float*)d_in[12], (const float*)d_in[16]};
  const float* eb1[4] = {(const float*)d_in[5], (const float*)d_in[9],  (const float*)d_in[13], (const float*)d_in[17]};
  const float* ew2[4] = {(const float*)d_in[6], (const float*)d_in[10], (const float*)d_in[14], (const float*)d_in[18]};
  const float* eb2[4] = {(const float*)d_in[7], (const float*)d_in[11], (const float*)d_in[15], (const float*)d_in[19]};
  const float* Wk = (const float*)d_in[20]; const float* bk = (const float*)d_in[21];
  const float* Wq = (const float*)d_in[22]; const float* bq = (const float*)d_in[23];
  const float* Wv = (const float*)d_in[24]; const float* bv = (const float*)d_in[25];
  const float* Wa = (const float*)d_in[26]; const float* ba = (const float*)d_in[27];
  const float* rel_att = (const float*)d_in[28];
  const float* rel_msg = (const float*)d_in[29];
  const float* rel_pri = (const float*)d_in[30];
  const float* skp = (const float*)d_in[31];
  const float* gma = (const float*)d_in[32];
  const float* bta = (const float*)d_in[33];
  const int* edge_index = (const int*)d_in[35];
  const int* edge_types = (const int*)d_in[36];
  float* out = (float*)d_out;
  char* ws = (char*)d_ws;

  u16*   kvb   = (u16*)  (ws + 0L);
  float* trans = (float*)(ws + 0L);
  u16*   qb    = (u16*)  (ws + 51200000L);
  u16*   gA    = (u16*)  (ws + 51200000L);
  u16*   wt    = (u16*)  (ws + 76800000L);
  u16*   hbf   = (u16*)  (ws + 76800000L);
  u16*   hid   = (u16*)  (ws + 102400000L);
  float* attb  = (float*)(ws + 230400000L);
  int*   bsum  = (int*)  (ws + 230400000L);
  int*   ss    = (int*)  (ws + 240000000L);
  int*   sd    = (int*)  (ws + 242400000L);
  int*   dp    = (int*)  (ws + 244800000L);
  int*   rowp  = (int*)  (ws + 247200000L);
  int*   curs  = (int*)  (ws + 247600128L);
  u16*   relpk = (u16*)  (ws + 247600128L);
  int*   meta  = (int*)  (ws + 248000128L);
  u16*   w1t   = (u16*)  (ws + 248000384L);
  u16*   w2t   = (u16*)  (ws + 248491904L);
  u16*   wkt   = (u16*)  (ws + 248754048L);
  u16*   wqt   = (u16*)  (ws + 249016192L);
  u16*   wvt   = (u16*)  (ws + 249278336L);
  u16*   wat   = (u16*)  (ws + 249540480L);

  int  di[4]  = {512, 256, 128, 64};
  long w1o[4] = {0, 131072, 196608, 229376};

  for (int i = 0; i < 4; i++){
    cast_tr<<<dim3(di[i], 1), 256, 0, stream>>>(ew1[i], w1t + w1o[i], di[i], 256);
    cast_tr<<<dim3(128, 1),  256, 0, stream>>>(ew2[i], w2t + (long)i * 32768, 256, 128);
  }
  cast_tr<<<dim3(64, 8), 256, 0, stream>>>(Wk, wkt, 128, 128);
  cast_tr<<<dim3(64, 8), 256, 0, stream>>>(Wq, wqt, 128, 128);
  cast_tr<<<dim3(64, 8), 256, 0, stream>>>(Wv, wvt, 128, 128);
  cast_tr<<<dim3(64, 8), 256, 0, stream>>>(Wa, wat, 128, 128);

  hipMemsetAsync(meta, 0, 256, stream);
  hist_k   <<<2344, 256, 0, stream>>>(edge_types, meta);
  scan_k   <<<1, 64, 0, stream>>>(meta);
  scatter_k<<<2344, 256, 0, stream>>>(edge_index, edge_types, meta, ss, sd);

  hipMemsetAsync(curs, 0, 400000, stream);
  hist_dst <<<2344, 256, 0, stream>>>(sd, curs);
  scan_part<<<391, 256, 0, stream>>>(curs, bsum);
  scan_bsum<<<1, 512, 0, stream>>>(bsum, 391);
  scan_fin <<<391, 256, 0, stream>>>(curs, bsum, rowp, curs);
  dp_scat  <<<2344, 256, 0, stream>>>(sd, curs, dp);

  pack_rel<<<512, 256, 0, stream>>>(rel_att, rel_msg, relpk);

  for (int i = 0; i < 4; i++){
    gemm_k<true,  true,  false, true><<<dim3(196, 2, 1), 256, 0, stream>>>(
        nf[i], w1t + w1o[i], eb1[i], nullptr, hid, NPT, 256, di[i], 0, 0, 0, 0, 256, 0);
    gemm_k<false, false, true,  true><<<dim3(196, 1, 1), 256, 0, stream>>>(
        hid, w2t + (long)i * 32768, eb2[i],
        out + (long)i * NPT * HD, hbf + (long)i * NPT * HD, NPT, 128, 256, 0, 0, 0, 0, 128, 0);
  }

  for (int l = 0; l < 2; l++){
    gemm_k<false, false, false, true><<<dim3(196, 1, 4), 256, 0, stream>>>(
        hbf, wkt + (long)l * 65536, bk + l * 512, nullptr, kvb,
        NPT, 128, 128, NPT, 16384, 128, NPT, 256, 0);
    gemm_k<false, false, false, true><<<dim3(196, 1, 4), 256, 0, stream>>>(
        hbf, wvt + (long)l * 65536, bv + l * 512, nullptr, kvb,
        NPT, 128, 128, NPT, 16384, 128, NPT, 256, 128);
    gemm_k<false, false, false, true><<<dim3(196, 1, 4), 256, 0, stream>>>(
        hbf, wqt + (long)l * 65536, bq + l * 512, nullptr, qb,
        NPT, 128, 128, NPT, 16384, 128, NPT, 128, 0);

    edge_fused<<<dim3(1200, 8), 256, 0, stream>>>(
        kvb, qb, ss, sd, dp, meta + 16, relpk, rel_pri + l * 32, attb, wt, l);

    seg_reduce<<<25000, 256, 0, stream>>>(attb, wt, rowp, gA);

    gemm_k<false, false, true, false><<<dim3(196, 1, 4), 256, 0, stream>>>(
        gA, wat + (long)l * 65536, ba + l * 512, trans, nullptr,
        NPT, 128, 128, NPT, 16384, 128, NPT, 128, 0);

    combine_ln<<<25000, 256, 0, stream>>>(
        trans, out, hbf, skp + l * 4, gma + l * 128, bta + l * 128);
  }
}